// Round 5
// baseline (179.599 us; speedup 1.0000x reference)
//
#include <hip/hip_runtime.h>
#include <hip/hip_fp16.h>
#include <math.h>

#define BB 128
#define HH 256
#define WW 256
#define HW 65536
#define OUT_B_STRIDE 196608   // 3*HW floats per batch in out

// Wave-local LDS fence: waits all this wave's LDS ops; "memory" clobber stops
// compiler reordering LDS ops across it. Cross-lane transposes here are all
// within one wave (in-order per-wave LDS pipe), so no s_barrier needed.
#define LDS_FENCE() asm volatile("s_waitcnt lgkmcnt(0)" ::: "memory")

typedef float f32x4_t __attribute__((ext_vector_type(4)));

// __builtin_nontemporal_store rejects HIP_vector_type<float,4>; go through a
// native clang vector (same 16B layout) -> global_store_dwordx4 ... nt
__device__ __forceinline__ void nt_store4(const float4 v, float4* p){
  f32x4_t t;
  t[0] = v.x; t[1] = v.y; t[2] = v.z; t[3] = v.w;
  __builtin_nontemporal_store(t, reinterpret_cast<f32x4_t*>(p));
}

__device__ __forceinline__ float2 cadd(float2 a, float2 b){ return make_float2(a.x+b.x, a.y+b.y); }
__device__ __forceinline__ float2 csub(float2 a, float2 b){ return make_float2(a.x-b.x, a.y-b.y); }

// a * b  (INV=false)  or  a * conj(b)  (INV=true)
template<bool INV>
__device__ __forceinline__ float2 cmul_t(float2 a, float2 b){
  if (INV) return make_float2(a.x*b.x + a.y*b.y, a.y*b.x - a.x*b.y);
  return make_float2(a.x*b.x - a.y*b.y, a.x*b.y + a.y*b.x);
}

template<bool INV>
__device__ __forceinline__ void fft4(float2&a,float2&b,float2&c,float2&d){
  float2 t0 = cadd(a,c), t1 = csub(a,c);
  float2 t2 = cadd(b,d), t3 = csub(b,d);
  float2 t3r = INV ? make_float2(-t3.y, t3.x) : make_float2(t3.y, -t3.x);
  a = cadd(t0,t2);
  b = cadd(t1,t3r);
  c = csub(t0,t2);
  d = csub(t1,t3r);
}

// 16-point DFT, natural-in natural-out, exponent e^{-2pi i jq/16} (conj if INV).
template<bool INV>
__device__ __forceinline__ void fft16(float2 x[16]){
  #pragma unroll
  for (int j0=0;j0<4;++j0) fft4<INV>(x[j0], x[j0+4], x[j0+8], x[j0+12]);
  const float WR[10] = {1.f, 0.923879533f, 0.707106781f, 0.382683432f, 0.f,
                        0.f, -0.707106781f, 0.f, 0.f, -0.923879533f};
  const float WI[10] = {0.f, -0.382683432f, -0.707106781f, -0.923879533f, -1.f,
                        0.f, -0.707106781f, 0.f, 0.f, 0.382683432f};
  #pragma unroll
  for (int q0=1;q0<4;++q0)
    #pragma unroll
    for (int j0=1;j0<4;++j0){
      int k = j0*q0;
      x[j0+4*q0] = cmul_t<INV>(x[j0+4*q0], make_float2(WR[k], WI[k]));
    }
  #pragma unroll
  for (int q0=0;q0<4;++q0) fft4<INV>(x[4*q0], x[4*q0+1], x[4*q0+2], x[4*q0+3]);
  float2 t[16];
  #pragma unroll
  for (int q0=0;q0<4;++q0)
    #pragma unroll
    for (int q1=0;q1<4;++q1) t[q0+4*q1] = x[4*q0+q1];
  #pragma unroll
  for (int i=0;i<16;++i) x[i]=t[i];
}

// Every wave builds ALL 256 twiddles (redundant identical writes across waves,
// benign) so tw reads need no block barrier — only a wave-local fence.
__device__ __forceinline__ void build_tw_all(float2* tw, int lane){
  #pragma unroll
  for (int k=0;k<4;++k){
    int idx = lane + 64*k;
    float s,c;
    __sincosf(-6.28318530717958647692f * (float)idx / 256.0f, &s, &c);
    tw[idx] = make_float2(c, s);
  }
}

__device__ __forceinline__ uint pkh2(float2 v){
  __half2 h = __float22half2_rn(v);
  return *(uint*)&h;
}
__device__ __forceinline__ float2 uph2(uint u){
  __half2 h = *(__half2*)&u;
  return __half22float2(h);
}

// Legacy shared union for the fallback kernels only.
union SharedU {
  float  xs[16*272];     // 17408 B
  float2 zbuf[16*273];   // 34944 B
  float  ybuf[16*272];
};

// Per-wave arena layout (main-path kernels): zarena[4368] float2 = 34944 B.
// Wave w owns float2 [w*1092 .. (w+1)*1092): holds either
//   xs_w  : 4 rows x 272 floats   (aliases start of arena)
//   zb_w  : 4 rows x 273 float2   (transpose buffer)
//   yb_w  : 4 rows x 272 floats   (K3 magnitude staging)
// All cross-lane traffic through an arena is within ONE wave; ordering is
// guaranteed by wave-lockstep instruction order + LDS_FENCE().

// ---------------- K1: row forward FFT (+ cidp prep in first 64 blocks) ----------------
// 16 rows/block, row groups are wave-local (r = 4*wid + lane>>4). ZERO barriers.
__global__ __launch_bounds__(256, 4) void k_row_fwd(const float* __restrict__ x,
                                                    __half2* __restrict__ S,
                                                    const int* __restrict__ cid,
                                                    unsigned char* __restrict__ cidp){
  __shared__ float2 zarena[4368];
  __shared__ float2 tw[256];
  int tid = threadIdx.x;
  int lane = tid & 63, wid = tid >> 6;
  int t = lane & 15, rl = lane >> 4;
  int r = (wid << 2) + rl;               // row in block 0..15, wave-grouped
  build_tw_all(tw, lane);

  // ---- cidp prep: cidp[p*256 + s*16 + k1] = cid[h2*256 + w2] ----
  if (blockIdx.x < 64){
    int g = (blockIdx.x*256 + tid) * 4;           // byte base
    int p  = g >> 8;
    int s  = (g >> 4) & 15;
    int k1b = g & 15;
    int wfreq = 16*(p & 15) + (p >> 4);
    int w2 = (wfreq + 128) & 255;
    uchar4 v4;
    unsigned char* vp = (unsigned char*)&v4;
    #pragma unroll
    for (int i=0;i<4;++i){
      int h2 = (16*(k1b+i) + s + 128) & 255;
      int cv = cid[h2*256 + w2];
      vp[i] = (unsigned char)cv;
    }
    *(uchar4*)(cidp + g) = v4;
  }

  // ---- stage x wave-privately: wave loads its own 4 rows (4KB contiguous) ----
  const float4* xb = (const float4*)x + (size_t)blockIdx.x * 1024;
  float* xsw = (float*)&zarena[wid*1092] + rl*272;
  #pragma unroll
  for (int j=0;j<4;++j){
    float4 v = xb[r*64 + t + 16*j];
    *(float4*)&xsw[4*(t + 16*j)] = v;
  }
  LDS_FENCE();                           // xs + tw writes done (this wave)
  float2 X[16];
  #pragma unroll
  for (int j=0;j<16;++j) X[j] = make_float2(xsw[16*j + t], 0.f);
  fft16<false>(X);
  #pragma unroll
  for (int q=0;q<16;++q) X[q] = cmul_t<false>(X[q], tw[t*q]);
  float2* zb = &zarena[wid*1092 + rl*273];
  #pragma unroll
  for (int q=0;q<16;++q) zb[q*17 + t] = X[q];   // overwrites xs region: same-wave,
  LDS_FENCE();                                  // read-instrs preceded write-instrs
  float2 Y[16];
  #pragma unroll
  for (int tt=0;tt<16;++tt) Y[tt] = zb[t*17 + tt];   // s = t
  fft16<false>(Y);                       // Y[k1] = X256[16k1 + s]
  int row = blockIdx.x*16 + r;
  int b = row >> 8, h = row & 255;
  uint4* dst = (uint4*)(S + (size_t)b*HW + h*256 + t*16);
  #pragma unroll
  for (int k=0;k<4;++k){
    uint4 q;
    q.x = pkh2(Y[4*k+0]); q.y = pkh2(Y[4*k+1]);
    q.z = pkh2(Y[4*k+2]); q.w = pkh2(Y[4*k+3]);
    dst[k] = q;
  }
}

// ---------------- K2: column fwd + mask + column inv (in place) ----------------
// Re-labeled lanes: g = lane&3 -> column (4 consecutive p per 4 lanes, 16B global
// clusters), t = lane>>2 -> FFT index. All 16-thread FFT groups wave-local.
// ZERO barriers. S is L2-resident so the 16B-sector traffic is L2-absorbed.
__global__ __launch_bounds__(256, 4) void k_col(__half2* __restrict__ S,
                                                const unsigned char* __restrict__ cidp,
                                                const float* __restrict__ pi){
  __shared__ float2 zarena[4368];
  __shared__ float2 tw[256];
  __shared__ float sPI[64];
  int tid = threadIdx.x;
  int lane = tid & 63, wid = tid >> 6;
  int g = lane & 3, t = lane >> 2;
  int c = (wid << 2) + g;                // column in block 0..15, wave-grouped
  int cg = blockIdx.x, b = blockIdx.y;
  build_tw_all(tw, lane);
  // every wave writes all 64 sPI entries (identical values) -> no barrier needed
  sPI[lane] = pi[(((b + 64) & 127) << 6) + lane] * 0.25f;  // batch-roll + 1/4 fold
  __half2* Sb = S + (size_t)b*HW;
  int p = cg*16 + c;
  float2 X[16];
  #pragma unroll
  for (int j=0;j<16;++j) X[j] = uph2(*(const uint*)&Sb[(16*j + t)*256 + p]);
  // mask bytes for this (p, s=t): one 16B load
  uint4 mq = *(const uint4*)(cidp + p*256 + t*16);
  LDS_FENCE();                           // tw + sPI (own wave's writes) visible
  fft16<false>(X);
  #pragma unroll
  for (int q=0;q<16;++q) X[q] = cmul_t<false>(X[q], tw[t*q]);
  float2* zb = &zarena[c*273];           // c = 4*wid+g -> arena region wave-local
  #pragma unroll
  for (int q=0;q<16;++q) zb[q*17 + t] = X[q];
  LDS_FENCE();
  float2 Y[16];
  #pragma unroll
  for (int tt=0;tt<16;++tt) Y[tt] = zb[t*17 + tt];
  fft16<false>(Y);                        // Y[k1] at h_freq = 16*k1 + s
  const uint* mw = (const uint*)&mq;
  #pragma unroll
  for (int k1=0;k1<16;++k1){
    int cv = (mw[k1>>2] >> ((k1&3)*8)) & 255;
    float m = (cv < 64) ? sPI[cv] : 0.25f;
    Y[k1].x *= m; Y[k1].y *= m;
  }
  fft16<true>(Y);
  #pragma unroll
  for (int u=0;u<16;++u) Y[u] = cmul_t<true>(Y[u], tw[u*t]);
  #pragma unroll
  for (int u=0;u<16;++u) zb[u*17 + t] = Y[u];
  LDS_FENCE();
  float2 R[16];
  #pragma unroll
  for (int k0=0;k0<16;++k0) R[k0] = zb[t*17 + k0];
  fft16<true>(R);
  #pragma unroll
  for (int j=0;j<16;++j){
    *(uint*)&Sb[(16*j + t)*256 + p] = pkh2(R[j]);
  }
}

// ---------------- K3 (fused): row inverse + abs + finalize ----------------
// Wave-local transposes; magnitude staged into the wave's own arena region;
// ONE barrier before the cross-wave float4 finalize.
__global__ __launch_bounds__(256, 4) void k_row_inv_fused(const __half2* __restrict__ S,
                                                          const float* __restrict__ x,
                                                          const float* __restrict__ pi,
                                                          float* __restrict__ out){
  __shared__ float2 zarena[4368];
  __shared__ float2 tw[256];
  int tid = threadIdx.x;
  int lane = tid & 63, wid = tid >> 6;
  int s = lane & 15, rl = lane >> 4;
  int r = (wid << 2) + rl;               // row in block, wave-grouped
  int slice = blockIdx.x, b = blockIdx.y;
  build_tw_all(tw, lane);
  int h = slice*16 + r;
  const uint4* src = (const uint4*)(S + (size_t)b*HW + h*256 + s*16);
  float2 X[16];
  #pragma unroll
  for (int k=0;k<4;++k){
    uint4 q = src[k];
    X[4*k+0] = uph2(q.x); X[4*k+1] = uph2(q.y);
    X[4*k+2] = uph2(q.z); X[4*k+3] = uph2(q.w);
  }
  LDS_FENCE();                           // tw writes (own wave) visible
  fft16<true>(X);
  #pragma unroll
  for (int u=0;u<16;++u) X[u] = cmul_t<true>(X[u], tw[u*s]);
  float2* zb = &zarena[wid*1092 + rl*273];
  #pragma unroll
  for (int u=0;u<16;++u) zb[u*17 + s] = X[u];
  LDS_FENCE();
  float2 R[16];
  #pragma unroll
  for (int k0=0;k0<16;++k0) R[k0] = zb[s*17 + k0];
  fft16<true>(R);
  const float scale = 1.0f/16384.0f;     // 1/65536 * 4 (mask carried 1/4)
  float* yb = (float*)&zarena[wid*1092] + rl*272;
  #pragma unroll
  for (int j=0;j<16;++j)
    yb[16*j + s] = sqrtf(R[j].x*R[j].x + R[j].y*R[j].y) * scale;
  __syncthreads();                       // finalize reads rows across waves
  const float4* x4 = (const float4*)x;
  float4* o4 = (float4*)out;
  size_t xbase = (size_t)b*16384 + slice*1024;
  size_t obase = (size_t)b*49152 + slice*1024;
  #pragma unroll
  for (int k=0;k<4;++k){
    int i2 = tid + k*256;
    int rr = i2 >> 6, c4 = i2 & 63;
    float4 y = *(float4*)((float*)&zarena[(rr>>2)*1092] + (rr&3)*272 + 4*c4);
    float4 xv = x4[xbase + i2];
    float4 df;
    df.x = fabsf(y.x - xv.x); df.y = fabsf(y.y - xv.y);
    df.z = fabsf(y.z - xv.z); df.w = fabsf(y.w - xv.w);
    // terminal, never re-read: nontemporal
    nt_store4(xv, &o4[obase + i2]);
    nt_store4(y,  &o4[obase + i2 + 16384]);
    nt_store4(df, &o4[obase + i2 + 32768]);
  }
  if (slice == 0 && b < 8){                 // PI tail: 8192 floats
    const float4* p4 = (const float4*)pi;
    nt_store4(p4[b*256 + tid], &o4[6291456 + b*256 + tid]);
  }
}

// ---------------- K3 (fallback): row inverse + abs -> y into ch0 ----------------
__global__ __launch_bounds__(256, 4) void k_row_inv_stage(const __half2* __restrict__ S,
                                                          float* __restrict__ out){
  __shared__ SharedU sh;
  __shared__ float2 tw[256];
  int tid = threadIdx.x;
  int s = tid & 15, r = tid >> 4;
  int slice = blockIdx.x, b = blockIdx.y;
  build_tw_all(tw, tid & 63);
  int h = slice*16 + r;
  const uint4* src = (const uint4*)(S + (size_t)b*HW + h*256 + s*16);
  float2 X[16];
  #pragma unroll
  for (int k=0;k<4;++k){
    uint4 q = src[k];
    X[4*k+0] = uph2(q.x); X[4*k+1] = uph2(q.y);
    X[4*k+2] = uph2(q.z); X[4*k+3] = uph2(q.w);
  }
  __syncthreads();
  fft16<true>(X);
  #pragma unroll
  for (int u=0;u<16;++u) X[u] = cmul_t<true>(X[u], tw[u*s]);
  #pragma unroll
  for (int u=0;u<16;++u) sh.zbuf[r*273 + u*17 + s] = X[u];
  __syncthreads();
  float2 R[16];
  #pragma unroll
  for (int k0=0;k0<16;++k0) R[k0] = sh.zbuf[r*273 + s*17 + k0];
  fft16<true>(R);
  const float scale = 1.0f/16384.0f;
  float* o = out + (size_t)b*OUT_B_STRIDE + h*256;
  #pragma unroll
  for (int j=0;j<16;++j)
    o[16*j + s] = sqrtf(R[j].x*R[j].x + R[j].y*R[j].y) * scale;
}

// ---------------- K4 (fallback): finalize ----------------
__global__ __launch_bounds__(256) void k_final(const float* __restrict__ x,
                                               const float* __restrict__ pi,
                                               float* __restrict__ out) {
  int i = blockIdx.x * 256 + threadIdx.x;
  const float4* x4 = (const float4*)x;
  float4* o4 = (float4*)out;
  int b = i >> 14;
  int r = i & 16383;
  int ch0 = b * 49152 + r;
  float4 y  = o4[ch0];
  float4 xv = x4[i];
  float4 df;
  df.x = fabsf(y.x - xv.x);
  df.y = fabsf(y.y - xv.y);
  df.z = fabsf(y.z - xv.z);
  df.w = fabsf(y.w - xv.w);
  nt_store4(xv, &o4[ch0]);
  nt_store4(y,  &o4[ch0 + 16384]);
  nt_store4(df, &o4[ch0 + 32768]);
  if (i < 2048) {
    const float4* p4 = (const float4*)pi;
    nt_store4(p4[i], &o4[6291456 + i]);
  }
}

extern "C" void kernel_launch(void* const* d_in, const int* in_sizes, int n_in,
                              void* d_out, int out_size, void* d_ws, size_t ws_size,
                              hipStream_t stream) {
  const float* x  = (const float*)d_in[0];
  const float* pi = (const float*)d_in[1];
  const int*  cid = (const int*)d_in[2];
  float* out = (float*)d_out;
  (void)in_sizes; (void)n_in; (void)out_size;

  const size_t S_bytes = (size_t)BB * HW * sizeof(__half2);   // 32 MB
  const size_t cidp_bytes = 65536;

  if (ws_size >= S_bytes + cidp_bytes) {
    __half2* S = (__half2*)d_ws;
    unsigned char* cidp = (unsigned char*)d_ws + S_bytes;
    k_row_fwd<<<2048, 256, 0, stream>>>(x, S, cid, cidp);
    k_col<<<dim3(16, BB), 256, 0, stream>>>(S, cidp, pi);
    k_row_inv_fused<<<dim3(16, BB), 256, 0, stream>>>(S, x, pi, out);
  } else {
    // S aliased into the upper half of out (32 MB region); y staged in ch0.
    __half2* S = (__half2*)out + (size_t)BB * HW;
    unsigned char* cidp = (unsigned char*)d_ws;  // needs 64 KB
    k_row_fwd<<<2048, 256, 0, stream>>>(x, S, cid, cidp);
    k_col<<<dim3(16, BB), 256, 0, stream>>>(S, cidp, pi);
    k_row_inv_stage<<<dim3(16, BB), 256, 0, stream>>>(S, out);
    k_final<<<8192, 256, 0, stream>>>(x, pi, out);
  }
}

// Round 7
// 179.241 us; speedup vs baseline: 1.0020x; 1.0020x over previous
//
#include <hip/hip_runtime.h>
#include <hip/hip_fp16.h>
#include <math.h>

#define BB 128
#define HH 256
#define WW 256
#define HW 65536
#define OUT_B_STRIDE 196608   // 3*HW floats per batch in out

// Wave-local LDS fence (K1 only): waits this wave's LDS ops; "memory" clobber
// stops compiler reordering. All cross-lane traffic in K1 is within one wave.
#define LDS_FENCE() asm volatile("s_waitcnt lgkmcnt(0)" ::: "memory")

typedef float f32x4_t __attribute__((ext_vector_type(4)));

// __builtin_nontemporal_store rejects HIP_vector_type<float,4>; go through a
// native clang vector (same 16B layout) -> global_store_dwordx4 ... nt
__device__ __forceinline__ void nt_store4(const float4 v, float4* p){
  f32x4_t t;
  t[0] = v.x; t[1] = v.y; t[2] = v.z; t[3] = v.w;
  __builtin_nontemporal_store(t, reinterpret_cast<f32x4_t*>(p));
}

__device__ __forceinline__ float2 cadd(float2 a, float2 b){ return make_float2(a.x+b.x, a.y+b.y); }
__device__ __forceinline__ float2 csub(float2 a, float2 b){ return make_float2(a.x-b.x, a.y-b.y); }

// a * b  (INV=false)  or  a * conj(b)  (INV=true)
template<bool INV>
__device__ __forceinline__ float2 cmul_t(float2 a, float2 b){
  if (INV) return make_float2(a.x*b.x + a.y*b.y, a.y*b.x - a.x*b.y);
  return make_float2(a.x*b.x - a.y*b.y, a.x*b.y + a.y*b.x);
}

template<bool INV>
__device__ __forceinline__ void fft4(float2&a,float2&b,float2&c,float2&d){
  float2 t0 = cadd(a,c), t1 = csub(a,c);
  float2 t2 = cadd(b,d), t3 = csub(b,d);
  float2 t3r = INV ? make_float2(-t3.y, t3.x) : make_float2(t3.y, -t3.x);
  a = cadd(t0,t2);
  b = cadd(t1,t3r);
  c = csub(t0,t2);
  d = csub(t1,t3r);
}

// 16-point DFT, natural-in natural-out, exponent e^{-2pi i jq/16} (conj if INV).
template<bool INV>
__device__ __forceinline__ void fft16(float2 x[16]){
  #pragma unroll
  for (int j0=0;j0<4;++j0) fft4<INV>(x[j0], x[j0+4], x[j0+8], x[j0+12]);
  const float WR[10] = {1.f, 0.923879533f, 0.707106781f, 0.382683432f, 0.f,
                        0.f, -0.707106781f, 0.f, 0.f, -0.923879533f};
  const float WI[10] = {0.f, -0.382683432f, -0.707106781f, -0.923879533f, -1.f,
                        0.f, -0.707106781f, 0.f, 0.f, 0.382683432f};
  #pragma unroll
  for (int q0=1;q0<4;++q0)
    #pragma unroll
    for (int j0=1;j0<4;++j0){
      int k = j0*q0;
      x[j0+4*q0] = cmul_t<INV>(x[j0+4*q0], make_float2(WR[k], WI[k]));
    }
  #pragma unroll
  for (int q0=0;q0<4;++q0) fft4<INV>(x[4*q0], x[4*q0+1], x[4*q0+2], x[4*q0+3]);
  float2 t[16];
  #pragma unroll
  for (int q0=0;q0<4;++q0)
    #pragma unroll
    for (int q1=0;q1<4;++q1) t[q0+4*q1] = x[4*q0+q1];
  #pragma unroll
  for (int i=0;i<16;++i) x[i]=t[i];
}

// Every wave builds ALL 256 twiddles (redundant identical writes across waves,
// benign) — safe under both fence-only (K1) and barrier (K2/K3) schedules.
__device__ __forceinline__ void build_tw_all(float2* tw, int lane){
  #pragma unroll
  for (int k=0;k<4;++k){
    int idx = lane + 64*k;
    float s,c;
    __sincosf(-6.28318530717958647692f * (float)idx / 256.0f, &s, &c);
    tw[idx] = make_float2(c, s);
  }
}

__device__ __forceinline__ uint pkh2(float2 v){
  __half2 h = __float22half2_rn(v);
  return *(uint*)&h;
}
__device__ __forceinline__ float2 uph2(uint u){
  __half2 h = *(__half2*)&u;
  return __half22float2(h);
}

// Shared union for the barrier kernels (K2, K3, fallbacks).
union SharedU {
  float  xs[16*272];     // 17408 B
  float2 zbuf[16*273];   // 34944 B
  float  ybuf[16*272];
};

// ---------------- K1: row forward FFT, 2-for-1 real packing ----------------
// Grid 1024 blocks: block = 32 rows. Per wave: 4 groups of 16 threads; group
// rl does row PAIR (2rl, 2rl+1) of the wave's 8-row slab as ONE complex FFT
// Z = even + i*odd, then Hermitian unpack:
//   Xe = (Z[w]+conj(Z[-w]))/2,  Xo = (Z[w]-conj(Z[-w]))/(2i).
// Mirror of w=16*k1+t is t'=(16-t)&15, k1'=(15-k1+[t==0])&15.
// All LDS traffic wave-local -> fences only, ZERO barriers.
// Storage: S[b][h][p] __half2, p = t*16 + k1 encodes w_freq = 16*k1 + t.
__global__ __launch_bounds__(256, 4) void k_row_fwd(const float* __restrict__ x,
                                                    __half2* __restrict__ S,
                                                    const int* __restrict__ cid,
                                                    unsigned char* __restrict__ cidp){
  __shared__ float2 zarena[4368];   // wave w owns [w*1092 .. (w+1)*1092)
  __shared__ float2 tw[256];
  int tid = threadIdx.x;
  int lane = tid & 63, wid = tid >> 6;
  int t = lane & 15, rl = lane >> 4;     // group-in-wave 0..3
  build_tw_all(tw, lane);

  // ---- cidp prep: cidp[p*256 + s*16 + k1] = cid[h2*256 + w2] ----
  if (blockIdx.x < 64){
    int g = (blockIdx.x*256 + tid) * 4;           // byte base
    int p  = g >> 8;
    int s  = (g >> 4) & 15;
    int k1b = g & 15;
    int wfreq = 16*(p & 15) + (p >> 4);
    int w2 = (wfreq + 128) & 255;
    uchar4 v4;
    unsigned char* vp = (unsigned char*)&v4;
    #pragma unroll
    for (int i=0;i<4;++i){
      int h2 = (16*(k1b+i) + s + 128) & 255;
      int cv = cid[h2*256 + w2];
      vp[i] = (unsigned char)cv;
    }
    *(uchar4*)(cidp + g) = v4;
  }

  // ---- stage 32 rows; wave w loads its own 8 rows ----
  const float4* xb = (const float4*)x + (size_t)blockIdx.x * 2048;
  float* xsw = (float*)&zarena[wid*1092];          // 8 rows x 272 floats
  #pragma unroll
  for (int j=0;j<8;++j){
    float4 v = xb[(wid*8 + j)*64 + lane];          // row j of wave slab
    *(float4*)&xsw[j*272 + lane*4] = v;
  }
  LDS_FENCE();                            // xs + tw writes done (this wave)

  // ---- Z = row(2rl) + i*row(2rl+1) ----
  float2 Z[16];
  #pragma unroll
  for (int j=0;j<16;++j)
    Z[j] = make_float2(xsw[(2*rl)*272 + 16*j + t],
                       xsw[(2*rl+1)*272 + 16*j + t]);
  fft16<false>(Z);
  #pragma unroll
  for (int q=0;q<16;++q) Z[q] = cmul_t<false>(Z[q], tw[t*q]);
  float2* zb = &zarena[wid*1092 + rl*273];  // aliases xs: reads issued first, in-order pipe
  #pragma unroll
  for (int q=0;q<16;++q) zb[q*17 + t] = Z[q];
  LDS_FENCE();
  float2 Y[16];
  #pragma unroll
  for (int tt=0;tt<16;++tt) Y[tt] = zb[t*17 + tt];
  fft16<false>(Y);                        // Y[k1] = Z256[16*k1 + t]

  // ---- Hermitian unpack: need conj(Z256[(256-w) mod 256]) ----
  #pragma unroll
  for (int k1=0;k1<16;++k1) zb[k1*17 + t] = Y[k1];   // natural layout [k1][t]
  LDS_FENCE();
  int sel = (t == 0) ? 1 : 0;
  int tp = (16 - t) & 15;
  uint qE[16], qO[16];
  #pragma unroll
  for (int k1=0;k1<16;++k1){
    float2 M = zb[((15 - k1 + sel) & 15)*17 + tp];
    float2 Ze = make_float2(0.5f*(Y[k1].x + M.x), 0.5f*(Y[k1].y - M.y));
    float2 Zo = make_float2(0.5f*(Y[k1].y + M.y), 0.5f*(M.x - Y[k1].x));
    qE[k1] = pkh2(Ze);
    qO[k1] = pkh2(Zo);
  }

  // ---- store both rows, p = t*16 + k1 layout as before ----
  int row0 = blockIdx.x*32 + (wid<<3) + 2*rl;   // global even row
  int b = row0 >> 8, h = row0 & 255;
  uint4* dstE = (uint4*)(S + (size_t)b*HW + h*256 + t*16);
  uint4* dstO = (uint4*)(S + (size_t)b*HW + (h+1)*256 + t*16);
  #pragma unroll
  for (int k=0;k<4;++k){
    uint4 qe; qe.x = qE[4*k+0]; qe.y = qE[4*k+1]; qe.z = qE[4*k+2]; qe.w = qE[4*k+3];
    uint4 qo; qo.x = qO[4*k+0]; qo.y = qO[4*k+1]; qo.z = qO[4*k+2]; qo.w = qO[4*k+3];
    dstE[k] = qe;
    dstO[k] = qo;
  }
}

// ---------------- K2: column fwd + mask + column inv (in place) ----------------
// R3 barrier form (measured fastest): c = tid&15 -> 64B global clusters.
__global__ __launch_bounds__(256, 4) void k_col(__half2* __restrict__ S,
                                                const unsigned char* __restrict__ cidp,
                                                const float* __restrict__ pi){
  __shared__ SharedU sh;
  __shared__ float2 tw[256];
  __shared__ float sPI[64];
  int tid = threadIdx.x;
  int c = tid & 15, t = tid >> 4;
  int cg = blockIdx.x, b = blockIdx.y;
  build_tw_all(tw, tid & 63);
  if (tid < 64) sPI[tid] = pi[(((b + 64) & 127) << 6) + tid] * 0.25f;  // batch-roll + 1/4 fold
  __half2* Sb = S + (size_t)b*HW;
  int p = cg*16 + c;
  float2 X[16];
  #pragma unroll
  for (int j=0;j<16;++j) X[j] = uph2(*(const uint*)&Sb[(16*j + t)*256 + p]);
  // mask bytes for this (p, s=t): one 16B load
  uint4 mq = *(const uint4*)(cidp + p*256 + t*16);
  __syncthreads();
  fft16<false>(X);
  #pragma unroll
  for (int q=0;q<16;++q) X[q] = cmul_t<false>(X[q], tw[t*q]);
  #pragma unroll
  for (int q=0;q<16;++q) sh.zbuf[c*273 + q*17 + t] = X[q];
  __syncthreads();
  int s = t;
  float2 Y[16];
  #pragma unroll
  for (int tt=0;tt<16;++tt) Y[tt] = sh.zbuf[c*273 + s*17 + tt];
  fft16<false>(Y);                        // Y[k1] at h_freq = 16*k1 + s
  const uint* mw = (const uint*)&mq;
  #pragma unroll
  for (int k1=0;k1<16;++k1){
    int cv = (mw[k1>>2] >> ((k1&3)*8)) & 255;
    float m = (cv < 64) ? sPI[cv] : 0.25f;
    Y[k1].x *= m; Y[k1].y *= m;
  }
  __syncthreads();
  fft16<true>(Y);
  #pragma unroll
  for (int u=0;u<16;++u) Y[u] = cmul_t<true>(Y[u], tw[u*s]);
  #pragma unroll
  for (int u=0;u<16;++u) sh.zbuf[c*273 + u*17 + s] = Y[u];
  __syncthreads();
  float2 R[16];
  #pragma unroll
  for (int k0=0;k0<16;++k0) R[k0] = sh.zbuf[c*273 + t*17 + k0];
  fft16<true>(R);
  #pragma unroll
  for (int j=0;j<16;++j){
    *(uint*)&Sb[(16*j + t)*256 + p] = pkh2(R[j]);
  }
}

// ---------------- K3 (fused): row inverse + abs + finalize ----------------
// R3 barrier form + nt terminal stores.
__global__ __launch_bounds__(256, 4) void k_row_inv_fused(const __half2* __restrict__ S,
                                                          const float* __restrict__ x,
                                                          const float* __restrict__ pi,
                                                          float* __restrict__ out){
  __shared__ SharedU sh;
  __shared__ float2 tw[256];
  int tid = threadIdx.x;
  int s = tid & 15, r = tid >> 4;
  int slice = blockIdx.x, b = blockIdx.y;
  build_tw_all(tw, tid & 63);
  int h = slice*16 + r;
  const uint4* src = (const uint4*)(S + (size_t)b*HW + h*256 + s*16);
  float2 X[16];
  #pragma unroll
  for (int k=0;k<4;++k){
    uint4 q = src[k];
    X[4*k+0] = uph2(q.x); X[4*k+1] = uph2(q.y);
    X[4*k+2] = uph2(q.z); X[4*k+3] = uph2(q.w);
  }
  __syncthreads();
  fft16<true>(X);
  #pragma unroll
  for (int u=0;u<16;++u) X[u] = cmul_t<true>(X[u], tw[u*s]);
  #pragma unroll
  for (int u=0;u<16;++u) sh.zbuf[r*273 + u*17 + s] = X[u];
  __syncthreads();
  float2 R[16];
  #pragma unroll
  for (int k0=0;k0<16;++k0) R[k0] = sh.zbuf[r*273 + s*17 + k0];
  fft16<true>(R);
  __syncthreads();                          // zbuf reads done; ybuf aliases
  const float scale = 1.0f/16384.0f;        // 1/65536 * 4 (mask carried 1/4)
  #pragma unroll
  for (int j=0;j<16;++j)
    sh.ybuf[r*272 + 16*j + s] = sqrtf(R[j].x*R[j].x + R[j].y*R[j].y) * scale;
  __syncthreads();
  const float4* x4 = (const float4*)x;
  float4* o4 = (float4*)out;
  size_t xbase = (size_t)b*16384 + slice*1024;
  size_t obase = (size_t)b*49152 + slice*1024;
  #pragma unroll
  for (int k=0;k<4;++k){
    int i2 = tid + k*256;
    int rr = i2 >> 6, c4 = i2 & 63;
    float4 y = *(float4*)&sh.ybuf[rr*272 + c4*4];
    float4 xv = x4[xbase + i2];
    float4 df;
    df.x = fabsf(y.x - xv.x); df.y = fabsf(y.y - xv.y);
    df.z = fabsf(y.z - xv.z); df.w = fabsf(y.w - xv.w);
    // terminal, never re-read: nontemporal
    nt_store4(xv, &o4[obase + i2]);
    nt_store4(y,  &o4[obase + i2 + 16384]);
    nt_store4(df, &o4[obase + i2 + 32768]);
  }
  if (slice == 0 && b < 8){                 // PI tail: 8192 floats
    const float4* p4 = (const float4*)pi;
    nt_store4(p4[b*256 + tid], &o4[6291456 + b*256 + tid]);
  }
}

// ---------------- K3 (fallback): row inverse + abs -> y into ch0 ----------------
__global__ __launch_bounds__(256, 4) void k_row_inv_stage(const __half2* __restrict__ S,
                                                          float* __restrict__ out){
  __shared__ SharedU sh;
  __shared__ float2 tw[256];
  int tid = threadIdx.x;
  int s = tid & 15, r = tid >> 4;
  int slice = blockIdx.x, b = blockIdx.y;
  build_tw_all(tw, tid & 63);
  int h = slice*16 + r;
  const uint4* src = (const uint4*)(S + (size_t)b*HW + h*256 + s*16);
  float2 X[16];
  #pragma unroll
  for (int k=0;k<4;++k){
    uint4 q = src[k];
    X[4*k+0] = uph2(q.x); X[4*k+1] = uph2(q.y);
    X[4*k+2] = uph2(q.z); X[4*k+3] = uph2(q.w);
  }
  __syncthreads();
  fft16<true>(X);
  #pragma unroll
  for (int u=0;u<16;++u) X[u] = cmul_t<true>(X[u], tw[u*s]);
  #pragma unroll
  for (int u=0;u<16;++u) sh.zbuf[r*273 + u*17 + s] = X[u];
  __syncthreads();
  float2 R[16];
  #pragma unroll
  for (int k0=0;k0<16;++k0) R[k0] = sh.zbuf[r*273 + s*17 + k0];
  fft16<true>(R);
  const float scale = 1.0f/16384.0f;
  float* o = out + (size_t)b*OUT_B_STRIDE + h*256;
  #pragma unroll
  for (int j=0;j<16;++j)
    o[16*j + s] = sqrtf(R[j].x*R[j].x + R[j].y*R[j].y) * scale;
}

// ---------------- K4 (fallback): finalize ----------------
__global__ __launch_bounds__(256) void k_final(const float* __restrict__ x,
                                               const float* __restrict__ pi,
                                               float* __restrict__ out) {
  int i = blockIdx.x * 256 + threadIdx.x;
  const float4* x4 = (const float4*)x;
  float4* o4 = (float4*)out;
  int b = i >> 14;
  int r = i & 16383;
  int ch0 = b * 49152 + r;
  float4 y  = o4[ch0];
  float4 xv = x4[i];
  float4 df;
  df.x = fabsf(y.x - xv.x);
  df.y = fabsf(y.y - xv.y);
  df.z = fabsf(y.z - xv.z);
  df.w = fabsf(y.w - xv.w);
  nt_store4(xv, &o4[ch0]);
  nt_store4(y,  &o4[ch0 + 16384]);
  nt_store4(df, &o4[ch0 + 32768]);
  if (i < 2048) {
    const float4* p4 = (const float4*)pi;
    nt_store4(p4[i], &o4[6291456 + i]);
  }
}

extern "C" void kernel_launch(void* const* d_in, const int* in_sizes, int n_in,
                              void* d_out, int out_size, void* d_ws, size_t ws_size,
                              hipStream_t stream) {
  const float* x  = (const float*)d_in[0];
  const float* pi = (const float*)d_in[1];
  const int*  cid = (const int*)d_in[2];
  float* out = (float*)d_out;
  (void)in_sizes; (void)n_in; (void)out_size;

  const size_t S_bytes = (size_t)BB * HW * sizeof(__half2);   // 32 MB
  const size_t cidp_bytes = 65536;

  if (ws_size >= S_bytes + cidp_bytes) {
    __half2* S = (__half2*)d_ws;
    unsigned char* cidp = (unsigned char*)d_ws + S_bytes;
    k_row_fwd<<<1024, 256, 0, stream>>>(x, S, cid, cidp);
    k_col<<<dim3(16, BB), 256, 0, stream>>>(S, cidp, pi);
    k_row_inv_fused<<<dim3(16, BB), 256, 0, stream>>>(S, x, pi, out);
  } else {
    // S aliased into the upper half of out (32 MB region); y staged in ch0.
    __half2* S = (__half2*)out + (size_t)BB * HW;
    unsigned char* cidp = (unsigned char*)d_ws;  // needs 64 KB
    k_row_fwd<<<1024, 256, 0, stream>>>(x, S, cid, cidp);
    k_col<<<dim3(16, BB), 256, 0, stream>>>(S, cidp, pi);
    k_row_inv_stage<<<dim3(16, BB), 256, 0, stream>>>(S, out);
    k_final<<<8192, 256, 0, stream>>>(x, pi, out);
  }
}